// Round 3
// baseline (417.025 us; speedup 1.0000x reference)
//
#include <hip/hip_runtime.h>
#include <hip/hip_bf16.h>

// GraphConvNorm: scatter-mean by (row*7+edge_type) -> [N,896]@[896,128] -> BatchNorm.
// N=100000, C=128, E=700000. x/w/gamma/beta f32, indices auto int32/int64, out f32.
// r8 post-mortem: gather-from-y hit a random-access throughput ceiling (~1.66 TB/s,
// concurrency doubling gave +6% only). y = x@W per type is 179 MB -> random 256B
// reads miss cache. r9 restructure: gather bf16(x) instead (25.6 MB, L2/L3-resident),
// build per-node type-means in registers (readfirstlane+switch on uniform t), stage
// [32,896] bf16 col_data in LDS (452-u32 padded rows vs 16-way bank conflict), fused
// MFMA GEMM vs packed W, write out f32 directly. y intermediate deleted entirely
// (-179MB write, -179MB random read). Overflow repair = on-the-fly matvec (Poisson(7)
// P(>32)~1e-13, never taken in practice); stats = separate streaming pass after ovf
// so no stats-repair algebra. r10: resubmit (r9 bench was an infra failure, no
// counters returned; source audit found no OOB/hang/alignment hazards).
// ws: xb 25.6MB + wp 0.23 + cnt 2.8 + fill 0.4 + ebuf 12.8 + ovf 2.8 + stats ~1KB.

typedef float  f32x4  __attribute__((ext_vector_type(4)));
typedef short  short8 __attribute__((ext_vector_type(8)));
typedef __bf16 bf16x8 __attribute__((ext_vector_type(8)));

union BFrag { uint4 q; short8 s; bf16x8 b; unsigned int u[4]; };

__device__ inline unsigned short f2bfbits(float f) {
    union { float f; unsigned int u; } v; v.f = f;
    unsigned int u = v.u;
    u += 0x7fffu + ((u >> 16) & 1u);   // RNE
    return (unsigned short)(u >> 16);
}
__device__ inline unsigned int pk_bf16(float lo, float hi) {
    float2 f; f.x = lo; f.y = hi;
    union { __hip_bfloat162 h; unsigned int u; } v;
    v.h = __float22bfloat162_rn(f);
    return v.u;
}
__device__ inline float bflo(unsigned int p) {
    union { unsigned int u; float f; } v; v.u = p << 16; return v.f;
}
__device__ inline float bfhi(unsigned int p) {
    union { unsigned int u; float f; } v; v.u = p & 0xffff0000u; return v.f;
}

#define BUCKET_CAP 32

// ---- W [7*128,128] f32 -> bf16 in MFMA B-frag order: [t][nt][kc][lane][j] ----
__global__ void pack_w(const float* __restrict__ w, short8* __restrict__ wp)
{
    int u = blockIdx.x * 256 + threadIdx.x;
    if (u >= 7 * 8 * 4 * 64) return;
    int lane = u & 63, kc = (u >> 6) & 3, nt = (u >> 8) & 7, t = u >> 11;
    int quad = lane >> 4, lr = lane & 15;
    short8 s;
#pragma unroll
    for (int j = 0; j < 8; ++j)
        s[j] = (short)f2bfbits(w[(size_t)(t * 128 + kc * 32 + quad * 8 + j) * 128
                                 + nt * 16 + lr]);
    wp[u] = s;
}

// ---- x [N,128] f32 -> bf16 packed u32 pairs: xbu[n*64+l] = ch(2l, 2l+1) ----
__global__ __launch_bounds__(256) void pack_x(const float* __restrict__ x,
                                              unsigned int* __restrict__ xbu,
                                              long total4)
{
    for (size_t v = (size_t)blockIdx.x * 256 + threadIdx.x; v < (size_t)total4;
         v += (size_t)gridDim.x * 256) {
        f32x4 t = *(const f32x4*)(x + v * 4);
        xbu[v * 2]     = pk_bf16(t[0], t[1]);
        xbu[v * 2 + 1] = pk_bf16(t[2], t[3]);
    }
}

// ---- index width autodetect ----
__global__ void flag_k(const int* __restrict__ row, int* __restrict__ flag)
{
    if (threadIdx.x == 0 && blockIdx.x == 0) {
        int s = 0;
#pragma unroll
        for (int i = 1; i < 64; i += 2) s |= row[i];
        flag[0] = (s == 0) ? 1 : 0;
    }
}
__device__ inline int idx_at(const int* __restrict__ p, int e, int mode) {
    return p[mode ? (e << 1) : e];
}

// ---- count + bucket (t=6 dead: self slot overwritten) ----
__global__ void edge_k(const int* __restrict__ row, const int* __restrict__ col,
                       const int* __restrict__ et, const int* __restrict__ flag,
                       unsigned int* __restrict__ cnt, unsigned int* __restrict__ fill,
                       int* __restrict__ ebuf, int* __restrict__ ovf,
                       int* __restrict__ novf, int E, int N)
{
    int e = blockIdx.x * blockDim.x + threadIdx.x;
    if (e >= E) return;
    const int mode = flag[0];
    int r = idx_at(row, e, mode);
    int c = idx_at(col, e, mode);
    int t = idx_at(et,  e, mode);
    if ((unsigned)r >= (unsigned)N || (unsigned)c >= (unsigned)N || (unsigned)t >= 6u)
        return;
    atomicAdd(&cnt[r * 7 + t], 1u);
    unsigned pos = atomicAdd(&fill[r], 1u);
    if (pos < BUCKET_CAP) ebuf[(size_t)r * BUCKET_CAP + pos] = (c << 3) | t;
    else                  ovf[atomicAdd(novf, 1)] = e;
}

// ---- fused gather(xb)->means->LDS->GEMM(wp)->out. 32 nodes/block, 4 waves. ----
// LDS col_data row = 452 u32 (448 data + 4 pad: stride%32==4 -> ~2-way confl only)
#define LROW 452
__global__ __launch_bounds__(256) void fused_k(
    const int* __restrict__ ebuf, const unsigned int* __restrict__ fill,
    const unsigned int* __restrict__ cnt, const unsigned int* __restrict__ xbu,
    const uint4* __restrict__ wpq, float* __restrict__ out, int N)
{
    __shared__ unsigned int cold[32 * LROW];   // 57856 B -> 2 blocks/CU
    const int tid  = threadIdx.x;
    const int l    = tid & 63;
    const int wv   = tid >> 6;
    const int quad = l >> 4, lr = l & 15;
    const int tile = blockIdx.x * 32;
    const int base = tile + wv * 8;

    // ================= phase 1: per-node type-means ====================
    unsigned fl = 0, cw = 1, self = 0; int pay = 0;
    if (base < N) {
        fl   = fill[base];
        pay  = ebuf[(size_t)base * BUCKET_CAP + l];     // lanes>=fill: garbage, never shfl'd
        cw   = (l < 7) ? cnt[base * 7 + l] : 1u;
        self = xbu[(size_t)base * 64 + l];
    }
    for (int i = 0; i < 8; ++i) {
        const int r = base + i;
        if (r < N) {
            const int   nE   = __builtin_amdgcn_readfirstlane((int)min(fl, (unsigned)BUCKET_CAP));
            const float civ  = 1.0f / (float)max(cw, 1u);
            const unsigned sv = self;
            const int   pcur = pay;
            float acc[6][2];
#pragma unroll
            for (int t = 0; t < 6; ++t) { acc[t][0] = 0.f; acc[t][1] = 0.f; }

            unsigned q[8]; int pj[8];
#pragma unroll
            for (int j = 0; j < 8; ++j)
                if (j < nE) {                       // scalar-uniform branch
                    pj[j] = __shfl(pcur, j);
                    q[j]  = xbu[(size_t)(pj[j] >> 3) * 64 + l];
                }
            // prefetch next node metadata under the edge-load latency
            if (i < 7 && r + 1 < N) {
                fl   = fill[r + 1];
                pay  = ebuf[(size_t)(r + 1) * BUCKET_CAP + l];
                cw   = (l < 7) ? cnt[(r + 1) * 7 + l] : 1u;
                self = xbu[(size_t)(r + 1) * 64 + l];
            }
#pragma unroll
            for (int j = 0; j < 8; ++j)
                if (j < nE) {
                    float lo = bflo(q[j]), hi = bfhi(q[j]);
                    switch (__builtin_amdgcn_readfirstlane(pj[j] & 7)) {
                        case 0: acc[0][0] += lo; acc[0][1] += hi; break;
                        case 1: acc[1][0] += lo; acc[1][1] += hi; break;
                        case 2: acc[2][0] += lo; acc[2][1] += hi; break;
                        case 3: acc[3][0] += lo; acc[3][1] += hi; break;
                        case 4: acc[4][0] += lo; acc[4][1] += hi; break;
                        default: acc[5][0] += lo; acc[5][1] += hi; break;
                    }
                }
            // rare tail: degree > 8
            for (int k = 8; k < nE; k += 8) {
                const int rem = nE - k;
#pragma unroll
                for (int j = 0; j < 8; ++j)
                    if (j < rem) {
                        pj[j] = __shfl(pcur, k + j);
                        q[j]  = xbu[(size_t)(pj[j] >> 3) * 64 + l];
                    }
#pragma unroll
                for (int j = 0; j < 8; ++j)
                    if (j < rem) {
                        float lo = bflo(q[j]), hi = bfhi(q[j]);
                        switch (__builtin_amdgcn_readfirstlane(pj[j] & 7)) {
                            case 0: acc[0][0] += lo; acc[0][1] += hi; break;
                            case 1: acc[1][0] += lo; acc[1][1] += hi; break;
                            case 2: acc[2][0] += lo; acc[2][1] += hi; break;
                            case 3: acc[3][0] += lo; acc[3][1] += hi; break;
                            case 4: acc[4][0] += lo; acc[4][1] += hi; break;
                            default: acc[5][0] += lo; acc[5][1] += hi; break;
                        }
                    }
            }
            // means -> LDS (bf16 pairs); self slot (t=6) = xb row verbatim
            const int mrow = (wv * 8 + i) * LROW;
#pragma unroll
            for (int t = 0; t < 6; ++t) {
                float iv = __shfl(civ, t);
                cold[mrow + t * 64 + l] = pk_bf16(acc[t][0] * iv, acc[t][1] * iv);
            }
            cold[mrow + 6 * 64 + l] = sv;
        }
    }
    __syncthreads();

    // ================= phase 2: [32,896] @ [896,128] ====================
    const int nt0 = wv * 2;
    f32x4 oa[2][2];
#pragma unroll
    for (int g = 0; g < 2; ++g)
#pragma unroll
        for (int p = 0; p < 2; ++p) oa[g][p] = (f32x4){0.f, 0.f, 0.f, 0.f};

    for (int t = 0; t < 7; ++t) {
#pragma unroll
        for (int kc = 0; kc < 4; ++kc) {
            BFrag a0, a1, b0, b1;
            const int ko = t * 64 + kc * 16 + quad * 4;
            a0.q = *(const uint4*)&cold[(lr)      * LROW + ko];
            a1.q = *(const uint4*)&cold[(16 + lr) * LROW + ko];
            b0.q = wpq[(size_t)(((t * 8 + nt0)     * 4 + kc) * 64) + l];
            b1.q = wpq[(size_t)(((t * 8 + nt0 + 1) * 4 + kc) * 64) + l];
            oa[0][0] = __builtin_amdgcn_mfma_f32_16x16x32_bf16(a0.b, b0.b, oa[0][0], 0, 0, 0);
            oa[0][1] = __builtin_amdgcn_mfma_f32_16x16x32_bf16(a0.b, b1.b, oa[0][1], 0, 0, 0);
            oa[1][0] = __builtin_amdgcn_mfma_f32_16x16x32_bf16(a1.b, b0.b, oa[1][0], 0, 0, 0);
            oa[1][1] = __builtin_amdgcn_mfma_f32_16x16x32_bf16(a1.b, b1.b, oa[1][1], 0, 0, 0);
        }
    }
    // epilogue: C/D col=lr -> ch=(nt0+p)*16+lr, row=quad*4+j -> node
#pragma unroll
    for (int g = 0; g < 2; ++g)
#pragma unroll
        for (int p = 0; p < 2; ++p)
#pragma unroll
            for (int j = 0; j < 4; ++j) {
                int m = tile + g * 16 + quad * 4 + j;
                if (m < N)
                    out[(size_t)m * 128 + (nt0 + p) * 16 + lr] = oa[g][p][j];
            }
}

// ---- overflow repair: on-the-fly matvec xb[c]@W[t]/cnt -> atomicAdd out ----
// (runs before stats_k so no stats correction needed; n>0 essentially never)
__global__ void ovf_k(const int* __restrict__ ovf, const int* __restrict__ novf,
                      const int* __restrict__ row, const int* __restrict__ col,
                      const int* __restrict__ et, const int* __restrict__ flag,
                      const unsigned int* __restrict__ xbu,
                      const unsigned int* __restrict__ cnt,
                      const float* __restrict__ w,
                      float* __restrict__ out, int nwaves)
{
    const int n = novf[0];
    if (n == 0) return;
    const int mode = flag[0];
    const int l = threadIdx.x & 63;
    for (int i = (blockIdx.x * 256 + threadIdx.x) >> 6; i < n; i += nwaves) {
        int e = ovf[i];
        int r = idx_at(row, e, mode);
        int c = idx_at(col, e, mode);
        int t = idx_at(et,  e, mode);
        float inv = 1.0f / (float)max(cnt[r * 7 + t], 1u);
        float d0 = 0.f, d1 = 0.f;
        for (int k = 0; k < 64; ++k) {
            unsigned xv = xbu[(size_t)c * 64 + k];
            float xlo = bflo(xv), xhi = bfhi(xv);
            const float* wr = w + (size_t)(t * 128 + 2 * k) * 128;
            d0 += xlo * wr[2 * l]     + xhi * wr[128 + 2 * l];
            d1 += xlo * wr[2 * l + 1] + xhi * wr[128 + 2 * l + 1];
        }
        atomicAdd(&out[(size_t)r * 128 + 2 * l],     d0 * inv);
        atomicAdd(&out[(size_t)r * 128 + 2 * l + 1], d1 * inv);
    }
}

// ---- BN stats: streaming reduce of out -> sums/sumsq per channel ----
__global__ __launch_bounds__(256) void stats_k(const float* __restrict__ out,
                                               float* __restrict__ stats, int N)
{
    const int tid = threadIdx.x;
    float s[4] = {0.f, 0.f, 0.f, 0.f}, s2[4] = {0.f, 0.f, 0.f, 0.f};
    const size_t nv = (size_t)N * 32;
    // grid(512)*256 threads * 4 f32 = 524288 f32, multiple of 128 -> fixed channels
    for (size_t v = (size_t)blockIdx.x * 256 + tid; v < nv;
         v += (size_t)gridDim.x * 256) {
        f32x4 x = *(const f32x4*)(out + v * 4);
#pragma unroll
        for (int j = 0; j < 4; ++j) { s[j] += x[j]; s2[j] += x[j] * x[j]; }
    }
    __shared__ float rs[256][8];
#pragma unroll
    for (int j = 0; j < 4; ++j) { rs[tid][j] = s[j]; rs[tid][j + 4] = s2[j]; }
    __syncthreads();
    if (tid < 32) {                                 // c0 = tid*4
        float v[8];
#pragma unroll
        for (int j = 0; j < 8; ++j) v[j] = rs[tid][j];
        for (int wgrp = 1; wgrp < 8; ++wgrp)
#pragma unroll
            for (int j = 0; j < 8; ++j) v[j] += rs[wgrp * 32 + tid][j];
#pragma unroll
        for (int j = 0; j < 4; ++j) {
            atomicAdd(&stats[tid * 4 + j],       v[j]);
            atomicAdd(&stats[128 + tid * 4 + j], v[j + 4]);
        }
    }
}

// ---- BN finalize: standard layout, coalesced vec4, no LDS ----
__global__ __launch_bounds__(256) void norm_k(
    float* __restrict__ out, const float* __restrict__ stats,
    const float* __restrict__ gamma, const float* __restrict__ beta, int N)
{
    const int c0 = (threadIdx.x * 4) & 127;     // grid stride is mult. of 128 elems
    const float invN = 1.0f / (float)N;
    f32x4 sc, bi;
#pragma unroll
    for (int j = 0; j < 4; ++j) {
        int c = c0 + j;
        float mean = stats[c] * invN;
        float var  = stats[128 + c] * invN - mean * mean;
        float s = gamma[c] * rsqrtf(var + 1e-5f);
        sc[j] = s; bi[j] = beta[c] - mean * s;
    }
    const size_t nv = (size_t)N * 32;           // vec4 count
    for (size_t v = (size_t)blockIdx.x * 256 + threadIdx.x; v < nv;
         v += (size_t)gridDim.x * 256) {
        f32x4 x = *(f32x4*)(out + v * 4);
#pragma unroll
        for (int j = 0; j < 4; ++j) x[j] = x[j] * sc[j] + bi[j];
        *(f32x4*)(out + v * 4) = x;
    }
}

extern "C" void kernel_launch(void* const* d_in, const int* in_sizes, int n_in,
                              void* d_out, int out_size, void* d_ws, size_t ws_size,
                              hipStream_t stream)
{
    const float* x     = (const float*)d_in[0];
    const int*   row   = (const int*)d_in[1];
    const int*   col   = (const int*)d_in[2];
    const int*   etype = (const int*)d_in[3];
    const float* w     = (const float*)d_in[4];
    const float* gamma = (const float*)d_in[5];
    const float* beta  = (const float*)d_in[6];
    float* out = (float*)d_out;

    const int N = in_sizes[0] / 128;   // 100000
    const int E = in_sizes[1];         // 700000

    char* ws = (char*)d_ws;
    unsigned int* xbu  = (unsigned int*)ws;                             // N*64 u32
    short8*       wp   = (short8*)(ws + (size_t)N * 256);               // 229376 B
    unsigned int* cnt  = (unsigned int*)((char*)wp + 7 * 8 * 4 * 64 * 16); // 7N u32
    unsigned int* fill = (unsigned int*)((char*)cnt + (size_t)N * 7 * 4);  // N u32
    int*          ebuf = (int*)((char*)fill + (size_t)N * 4);           // N*32 int
    int*          ovf  = (int*)((char*)ebuf + (size_t)N * BUCKET_CAP * 4); // E int
    float*        stats= (float*)((char*)ovf + (size_t)E * 4);          // 256 f32
    int*          flag = (int*)((char*)stats + 256 * 4);                // 1 int
    int*          novf = flag + 1;                                      // 1 int

    hipMemsetAsync(cnt,  0, (size_t)N * 7 * 4, stream);
    hipMemsetAsync(fill, 0, (size_t)N * 4,     stream);
    hipMemsetAsync(stats, 0, 256 * 4 + 8,      stream);

    flag_k<<<1, 64, 0, stream>>>(row, flag);
    pack_w<<<(7 * 8 * 4 * 64 + 255) / 256, 256, 0, stream>>>(w, wp);
    pack_x<<<2048, 256, 0, stream>>>(x, xbu, (long)N * 32);
    edge_k<<<(E + 255) / 256, 256, 0, stream>>>(row, col, etype, flag,
                                                cnt, fill, ebuf, ovf, novf, E, N);
    fused_k<<<(N + 31) / 32, 256, 0, stream>>>(ebuf, fill, cnt, xbu,
                                               (const uint4*)wp, out, N);
    ovf_k<<<64, 256, 0, stream>>>(ovf, novf, row, col, etype, flag,
                                  xbu, cnt, w, out, 256);
    stats_k<<<512, 256, 0, stream>>>(out, stats, N);
    norm_k<<<2048, 256, 0, stream>>>(out, stats, gamma, beta, N);
}

// Round 4
// 347.203 us; speedup vs baseline: 1.2011x; 1.2011x over previous
//
#include <hip/hip_runtime.h>
#include <hip/hip_bf16.h>

// GraphConvNorm: scatter-mean by (row*7+edge_type) -> [N,896]@[896,128] -> BatchNorm.
// N=100000, C=128, E=700000. x/w/gamma/beta f32, indices auto int32/int64, out f32.
// r9/r10: fused gather(bf16 x, 25.6MB L2/L3-resident)->means->LDS->MFMA GEMM; deleted
// the 179MB y intermediate. r10 post-mortem: fused_k 177us at 20% occupancy — 57.8KB
// LDS capped 2 blocks/CU (8 waves/CU); random-gather request rate scaled with
// occupancy (gather_k: 9.7 G req/s @60% occ; fused_k: 4.4 G @20%). Fusion was right
// (FETCH 99->88MB), occupancy was the regression. r11: 16-node tiles -> LDS 28.9KB ->
// 5 blocks/CU, 20 waves/CU (62%), VGPR limit (~88) matches. N=6250*16 exactly.
// Also: ebuf read limited to lanes<32 (cap=32) -> -12.8MB FETCH.
// ws: xb 25.6MB + wp 0.23 + cnt 2.8 + fill 0.4 + ebuf 12.8 + ovf 2.8 + stats ~1KB.

typedef float  f32x4  __attribute__((ext_vector_type(4)));
typedef short  short8 __attribute__((ext_vector_type(8)));
typedef __bf16 bf16x8 __attribute__((ext_vector_type(8)));

union BFrag { uint4 q; short8 s; bf16x8 b; unsigned int u[4]; };

__device__ inline unsigned short f2bfbits(float f) {
    union { float f; unsigned int u; } v; v.f = f;
    unsigned int u = v.u;
    u += 0x7fffu + ((u >> 16) & 1u);   // RNE
    return (unsigned short)(u >> 16);
}
__device__ inline unsigned int pk_bf16(float lo, float hi) {
    float2 f; f.x = lo; f.y = hi;
    union { __hip_bfloat162 h; unsigned int u; } v;
    v.h = __float22bfloat162_rn(f);
    return v.u;
}
__device__ inline float bflo(unsigned int p) {
    union { unsigned int u; float f; } v; v.u = p << 16; return v.f;
}
__device__ inline float bfhi(unsigned int p) {
    union { unsigned int u; float f; } v; v.u = p & 0xffff0000u; return v.f;
}

#define BUCKET_CAP 32

// ---- W [7*128,128] f32 -> bf16 in MFMA B-frag order: [t][nt][kc][lane][j] ----
__global__ void pack_w(const float* __restrict__ w, short8* __restrict__ wp)
{
    int u = blockIdx.x * 256 + threadIdx.x;
    if (u >= 7 * 8 * 4 * 64) return;
    int lane = u & 63, kc = (u >> 6) & 3, nt = (u >> 8) & 7, t = u >> 11;
    int quad = lane >> 4, lr = lane & 15;
    short8 s;
#pragma unroll
    for (int j = 0; j < 8; ++j)
        s[j] = (short)f2bfbits(w[(size_t)(t * 128 + kc * 32 + quad * 8 + j) * 128
                                 + nt * 16 + lr]);
    wp[u] = s;
}

// ---- x [N,128] f32 -> bf16 packed u32 pairs: xbu[n*64+l] = ch(2l, 2l+1) ----
__global__ __launch_bounds__(256) void pack_x(const float* __restrict__ x,
                                              unsigned int* __restrict__ xbu,
                                              long total4)
{
    for (size_t v = (size_t)blockIdx.x * 256 + threadIdx.x; v < (size_t)total4;
         v += (size_t)gridDim.x * 256) {
        f32x4 t = *(const f32x4*)(x + v * 4);
        xbu[v * 2]     = pk_bf16(t[0], t[1]);
        xbu[v * 2 + 1] = pk_bf16(t[2], t[3]);
    }
}

// ---- index width autodetect ----
__global__ void flag_k(const int* __restrict__ row, int* __restrict__ flag)
{
    if (threadIdx.x == 0 && blockIdx.x == 0) {
        int s = 0;
#pragma unroll
        for (int i = 1; i < 64; i += 2) s |= row[i];
        flag[0] = (s == 0) ? 1 : 0;
    }
}
__device__ inline int idx_at(const int* __restrict__ p, int e, int mode) {
    return p[mode ? (e << 1) : e];
}

// ---- count + bucket (t=6 dead: self slot overwritten) ----
__global__ void edge_k(const int* __restrict__ row, const int* __restrict__ col,
                       const int* __restrict__ et, const int* __restrict__ flag,
                       unsigned int* __restrict__ cnt, unsigned int* __restrict__ fill,
                       int* __restrict__ ebuf, int* __restrict__ ovf,
                       int* __restrict__ novf, int E, int N)
{
    int e = blockIdx.x * blockDim.x + threadIdx.x;
    if (e >= E) return;
    const int mode = flag[0];
    int r = idx_at(row, e, mode);
    int c = idx_at(col, e, mode);
    int t = idx_at(et,  e, mode);
    if ((unsigned)r >= (unsigned)N || (unsigned)c >= (unsigned)N || (unsigned)t >= 6u)
        return;
    atomicAdd(&cnt[r * 7 + t], 1u);
    unsigned pos = atomicAdd(&fill[r], 1u);
    if (pos < BUCKET_CAP) ebuf[(size_t)r * BUCKET_CAP + pos] = (c << 3) | t;
    else                  ovf[atomicAdd(novf, 1)] = e;
}

// ---- fused gather(xb)->means->LDS->GEMM(wp)->out. 16 nodes/block, 4 waves. ----
// LDS row = 452 u32 (448 data + 4 pad; stride%32==4 -> <=2-way conflicts, free)
#define LROW 452
#define TNODES 16
__global__ __launch_bounds__(256) void fused_k(
    const int* __restrict__ ebuf, const unsigned int* __restrict__ fill,
    const unsigned int* __restrict__ cnt, const unsigned int* __restrict__ xbu,
    const uint4* __restrict__ wpq, float* __restrict__ out, int N)
{
    __shared__ unsigned int cold[TNODES * LROW];   // 28928 B -> 5 blocks/CU
    const int tid  = threadIdx.x;
    const int l    = tid & 63;
    const int wv   = tid >> 6;
    const int quad = l >> 4, lr = l & 15;
    const int tile = blockIdx.x * TNODES;
    const int base = tile + wv * 4;

    // ================= phase 1: per-node type-means (4 nodes/wave) =========
    unsigned fl = 0, cw = 1, self = 0; int pay = 0;
    if (base < N) {
        fl   = fill[base];
        pay  = (l < BUCKET_CAP) ? ebuf[(size_t)base * BUCKET_CAP + l] : 0;
        cw   = (l < 7) ? cnt[base * 7 + l] : 1u;
        self = xbu[(size_t)base * 64 + l];
    }
    for (int i = 0; i < 4; ++i) {
        const int r = base + i;
        if (r < N) {
            const int   nE   = __builtin_amdgcn_readfirstlane((int)min(fl, (unsigned)BUCKET_CAP));
            const float civ  = 1.0f / (float)max(cw, 1u);
            const unsigned sv = self;
            const int   pcur = pay;
            float acc[6][2];
#pragma unroll
            for (int t = 0; t < 6; ++t) { acc[t][0] = 0.f; acc[t][1] = 0.f; }

            unsigned q[8]; int pj[8];
#pragma unroll
            for (int j = 0; j < 8; ++j)
                if (j < nE) {                       // scalar-uniform branch
                    pj[j] = __shfl(pcur, j);
                    q[j]  = xbu[(size_t)(pj[j] >> 3) * 64 + l];
                }
            // prefetch next node metadata under the edge-load latency
            if (i < 3 && r + 1 < N) {
                fl   = fill[r + 1];
                pay  = (l < BUCKET_CAP) ? ebuf[(size_t)(r + 1) * BUCKET_CAP + l] : 0;
                cw   = (l < 7) ? cnt[(r + 1) * 7 + l] : 1u;
                self = xbu[(size_t)(r + 1) * 64 + l];
            }
#pragma unroll
            for (int j = 0; j < 8; ++j)
                if (j < nE) {
                    float lo = bflo(q[j]), hi = bfhi(q[j]);
                    switch (__builtin_amdgcn_readfirstlane(pj[j] & 7)) {
                        case 0: acc[0][0] += lo; acc[0][1] += hi; break;
                        case 1: acc[1][0] += lo; acc[1][1] += hi; break;
                        case 2: acc[2][0] += lo; acc[2][1] += hi; break;
                        case 3: acc[3][0] += lo; acc[3][1] += hi; break;
                        case 4: acc[4][0] += lo; acc[4][1] += hi; break;
                        default: acc[5][0] += lo; acc[5][1] += hi; break;
                    }
                }
            // rare tail: degree > 8
            for (int k = 8; k < nE; k += 8) {
                const int rem = nE - k;
#pragma unroll
                for (int j = 0; j < 8; ++j)
                    if (j < rem) {
                        pj[j] = __shfl(pcur, k + j);
                        q[j]  = xbu[(size_t)(pj[j] >> 3) * 64 + l];
                    }
#pragma unroll
                for (int j = 0; j < 8; ++j)
                    if (j < rem) {
                        float lo = bflo(q[j]), hi = bfhi(q[j]);
                        switch (__builtin_amdgcn_readfirstlane(pj[j] & 7)) {
                            case 0: acc[0][0] += lo; acc[0][1] += hi; break;
                            case 1: acc[1][0] += lo; acc[1][1] += hi; break;
                            case 2: acc[2][0] += lo; acc[2][1] += hi; break;
                            case 3: acc[3][0] += lo; acc[3][1] += hi; break;
                            case 4: acc[4][0] += lo; acc[4][1] += hi; break;
                            default: acc[5][0] += lo; acc[5][1] += hi; break;
                        }
                    }
            }
            // means -> LDS (bf16 pairs); self slot (t=6) = xb row verbatim
            const int mrow = (wv * 4 + i) * LROW;
#pragma unroll
            for (int t = 0; t < 6; ++t) {
                float iv = __shfl(civ, t);
                cold[mrow + t * 64 + l] = pk_bf16(acc[t][0] * iv, acc[t][1] * iv);
            }
            cold[mrow + 6 * 64 + l] = sv;
        }
    }
    __syncthreads();

    // ================= phase 2: [16,896] @ [896,128] ====================
    const int nt0 = wv * 2;
    f32x4 oa[2];
#pragma unroll
    for (int p = 0; p < 2; ++p) oa[p] = (f32x4){0.f, 0.f, 0.f, 0.f};

    for (int t = 0; t < 7; ++t) {
#pragma unroll
        for (int kc = 0; kc < 4; ++kc) {
            BFrag a0, b0, b1;
            const int ko = t * 64 + kc * 16 + quad * 4;
            a0.q = *(const uint4*)&cold[lr * LROW + ko];
            b0.q = wpq[(size_t)(((t * 8 + nt0)     * 4 + kc) * 64) + l];
            b1.q = wpq[(size_t)(((t * 8 + nt0 + 1) * 4 + kc) * 64) + l];
            oa[0] = __builtin_amdgcn_mfma_f32_16x16x32_bf16(a0.b, b0.b, oa[0], 0, 0, 0);
            oa[1] = __builtin_amdgcn_mfma_f32_16x16x32_bf16(a0.b, b1.b, oa[1], 0, 0, 0);
        }
    }
    // epilogue: C/D col=lr -> ch=(nt0+p)*16+lr, row=quad*4+j -> node
#pragma unroll
    for (int p = 0; p < 2; ++p)
#pragma unroll
        for (int j = 0; j < 4; ++j) {
            int m = tile + quad * 4 + j;
            if (m < N)
                out[(size_t)m * 128 + (nt0 + p) * 16 + lr] = oa[p][j];
        }
}

// ---- overflow repair: on-the-fly matvec xb[c]@W[t]/cnt -> atomicAdd out ----
// (runs before stats_k so no stats correction needed; n>0 essentially never)
__global__ void ovf_k(const int* __restrict__ ovf, const int* __restrict__ novf,
                      const int* __restrict__ row, const int* __restrict__ col,
                      const int* __restrict__ et, const int* __restrict__ flag,
                      const unsigned int* __restrict__ xbu,
                      const unsigned int* __restrict__ cnt,
                      const float* __restrict__ w,
                      float* __restrict__ out, int nwaves)
{
    const int n = novf[0];
    if (n == 0) return;
    const int mode = flag[0];
    const int l = threadIdx.x & 63;
    for (int i = (blockIdx.x * 256 + threadIdx.x) >> 6; i < n; i += nwaves) {
        int e = ovf[i];
        int r = idx_at(row, e, mode);
        int c = idx_at(col, e, mode);
        int t = idx_at(et,  e, mode);
        float inv = 1.0f / (float)max(cnt[r * 7 + t], 1u);
        float d0 = 0.f, d1 = 0.f;
        for (int k = 0; k < 64; ++k) {
            unsigned xv = xbu[(size_t)c * 64 + k];
            float xlo = bflo(xv), xhi = bfhi(xv);
            const float* wr = w + (size_t)(t * 128 + 2 * k) * 128;
            d0 += xlo * wr[2 * l]     + xhi * wr[128 + 2 * l];
            d1 += xlo * wr[2 * l + 1] + xhi * wr[128 + 2 * l + 1];
        }
        atomicAdd(&out[(size_t)r * 128 + 2 * l],     d0 * inv);
        atomicAdd(&out[(size_t)r * 128 + 2 * l + 1], d1 * inv);
    }
}

// ---- BN stats: streaming reduce of out -> sums/sumsq per channel ----
__global__ __launch_bounds__(256) void stats_k(const float* __restrict__ out,
                                               float* __restrict__ stats, int N)
{
    const int tid = threadIdx.x;
    float s[4] = {0.f, 0.f, 0.f, 0.f}, s2[4] = {0.f, 0.f, 0.f, 0.f};
    const size_t nv = (size_t)N * 32;
    // grid(512)*256 threads * 4 f32 = 524288 f32, multiple of 128 -> fixed channels
    for (size_t v = (size_t)blockIdx.x * 256 + tid; v < nv;
         v += (size_t)gridDim.x * 256) {
        f32x4 x = *(const f32x4*)(out + v * 4);
#pragma unroll
        for (int j = 0; j < 4; ++j) { s[j] += x[j]; s2[j] += x[j] * x[j]; }
    }
    __shared__ float rs[256][8];
#pragma unroll
    for (int j = 0; j < 4; ++j) { rs[tid][j] = s[j]; rs[tid][j + 4] = s2[j]; }
    __syncthreads();
    if (tid < 32) {                                 // c0 = tid*4
        float v[8];
#pragma unroll
        for (int j = 0; j < 8; ++j) v[j] = rs[tid][j];
        for (int wgrp = 1; wgrp < 8; ++wgrp)
#pragma unroll
            for (int j = 0; j < 8; ++j) v[j] += rs[wgrp * 32 + tid][j];
#pragma unroll
        for (int j = 0; j < 4; ++j) {
            atomicAdd(&stats[tid * 4 + j],       v[j]);
            atomicAdd(&stats[128 + tid * 4 + j], v[j + 4]);
        }
    }
}

// ---- BN finalize: standard layout, coalesced vec4, no LDS ----
__global__ __launch_bounds__(256) void norm_k(
    float* __restrict__ out, const float* __restrict__ stats,
    const float* __restrict__ gamma, const float* __restrict__ beta, int N)
{
    const int c0 = (threadIdx.x * 4) & 127;     // grid stride is mult. of 128 elems
    const float invN = 1.0f / (float)N;
    f32x4 sc, bi;
#pragma unroll
    for (int j = 0; j < 4; ++j) {
        int c = c0 + j;
        float mean = stats[c] * invN;
        float var  = stats[128 + c] * invN - mean * mean;
        float s = gamma[c] * rsqrtf(var + 1e-5f);
        sc[j] = s; bi[j] = beta[c] - mean * s;
    }
    const size_t nv = (size_t)N * 32;           // vec4 count
    for (size_t v = (size_t)blockIdx.x * 256 + threadIdx.x; v < nv;
         v += (size_t)gridDim.x * 256) {
        f32x4 x = *(f32x4*)(out + v * 4);
#pragma unroll
        for (int j = 0; j < 4; ++j) x[j] = x[j] * sc[j] + bi[j];
        *(f32x4*)(out + v * 4) = x;
    }
}

extern "C" void kernel_launch(void* const* d_in, const int* in_sizes, int n_in,
                              void* d_out, int out_size, void* d_ws, size_t ws_size,
                              hipStream_t stream)
{
    const float* x     = (const float*)d_in[0];
    const int*   row   = (const int*)d_in[1];
    const int*   col   = (const int*)d_in[2];
    const int*   etype = (const int*)d_in[3];
    const float* w     = (const float*)d_in[4];
    const float* gamma = (const float*)d_in[5];
    const float* beta  = (const float*)d_in[6];
    float* out = (float*)d_out;

    const int N = in_sizes[0] / 128;   // 100000
    const int E = in_sizes[1];         // 700000

    char* ws = (char*)d_ws;
    unsigned int* xbu  = (unsigned int*)ws;                             // N*64 u32
    short8*       wp   = (short8*)(ws + (size_t)N * 256);               // 229376 B
    unsigned int* cnt  = (unsigned int*)((char*)wp + 7 * 8 * 4 * 64 * 16); // 7N u32
    unsigned int* fill = (unsigned int*)((char*)cnt + (size_t)N * 7 * 4);  // N u32
    int*          ebuf = (int*)((char*)fill + (size_t)N * 4);           // N*32 int
    int*          ovf  = (int*)((char*)ebuf + (size_t)N * BUCKET_CAP * 4); // E int
    float*        stats= (float*)((char*)ovf + (size_t)E * 4);          // 256 f32
    int*          flag = (int*)((char*)stats + 256 * 4);                // 1 int
    int*          novf = flag + 1;                                      // 1 int

    hipMemsetAsync(cnt,  0, (size_t)N * 7 * 4, stream);
    hipMemsetAsync(fill, 0, (size_t)N * 4,     stream);
    hipMemsetAsync(stats, 0, 256 * 4 + 8,      stream);

    flag_k<<<1, 64, 0, stream>>>(row, flag);
    pack_w<<<(7 * 8 * 4 * 64 + 255) / 256, 256, 0, stream>>>(w, wp);
    pack_x<<<2048, 256, 0, stream>>>(x, xbu, (long)N * 32);
    edge_k<<<(E + 255) / 256, 256, 0, stream>>>(row, col, etype, flag,
                                                cnt, fill, ebuf, ovf, novf, E, N);
    fused_k<<<(N + TNODES - 1) / TNODES, 256, 0, stream>>>(ebuf, fill, cnt, xbu,
                                                           (const uint4*)wp, out, N);
    ovf_k<<<64, 256, 0, stream>>>(ovf, novf, row, col, etype, flag,
                                  xbu, cnt, w, out, 256);
    stats_k<<<512, 256, 0, stream>>>(out, stats, N);
    norm_k<<<2048, 256, 0, stream>>>(out, stats, gamma, beta, N);
}

// Round 5
// 264.813 us; speedup vs baseline: 1.5748x; 1.3111x over previous
//
#include <hip/hip_runtime.h>
#include <hip/hip_bf16.h>

// GraphConvNorm: scatter-mean by (row*7+edge_type) -> [N,896]@[896,128] -> BatchNorm.
// N=100000, C=128, E=700000. x/w/gamma/beta f32, indices auto int32/int64, out f32.
// r11: fused gather(bf16 x)->means->LDS->MFMA, 16-node tiles: 101us @48% occ,
// 15 G wave-req/s (vs 8.5 G @20% occ in r10) -> still occupancy-bound.
// r12: (a) 512-thread/8-wave blocks, same 16-node tile -> 4 blocks x 8 waves =
// 32 waves/CU (100%); phase-2 = one 16-col ntile per wave. (b) merged meta row
// [N][48]: w0-6 = overflow-only type counts, w7 = fill, w8-39 = payload -> ONE
// metadata request/node (was 3); in-bucket type counts re-derived free via ballot;
// edge_k drops the cnt atomic (2->1 atomics/edge). (c) BN stats fused into fused_k
// epilogue (lane channel fixed = wv*16+lr; quad-reduce via shfl_xor; 8-replica
// stats to spread atomic contention) -> stats_k pass deleted. ovf_k repairs out
// AND stats (replica 0) exactly via returned-old algebra; counts reconstructed
// from ballot+meta. ws: xb 25.6MB + wp 0.23 + meta 19.2MB + ovf 2.8 + stats 8KB.

typedef float  f32x4  __attribute__((ext_vector_type(4)));
typedef short  short8 __attribute__((ext_vector_type(8)));
typedef __bf16 bf16x8 __attribute__((ext_vector_type(8)));

union BFrag { uint4 q; short8 s; bf16x8 b; unsigned int u[4]; };

__device__ inline unsigned short f2bfbits(float f) {
    union { float f; unsigned int u; } v; v.f = f;
    unsigned int u = v.u;
    u += 0x7fffu + ((u >> 16) & 1u);   // RNE
    return (unsigned short)(u >> 16);
}
__device__ inline unsigned int pk_bf16(float lo, float hi) {
    float2 f; f.x = lo; f.y = hi;
    union { __hip_bfloat162 h; unsigned int u; } v;
    v.h = __float22bfloat162_rn(f);
    return v.u;
}
__device__ inline float bflo(unsigned int p) {
    union { unsigned int u; float f; } v; v.u = p << 16; return v.f;
}
__device__ inline float bfhi(unsigned int p) {
    union { unsigned int u; float f; } v; v.u = p & 0xffff0000u; return v.f;
}

#define BUCKET_CAP 32
#define ROWW 48          // meta row: 0-6 ovf-cnt, 7 fill, 8-39 payload, 40-47 pad
#define LROW 452         // LDS row u32 (448 data + 4 pad)
#define TNODES 16

// ---- W [7*128,128] f32 -> bf16 in MFMA B-frag order: [t][nt][kc][lane][j] ----
__global__ void pack_w(const float* __restrict__ w, short8* __restrict__ wp)
{
    int u = blockIdx.x * 256 + threadIdx.x;
    if (u >= 7 * 8 * 4 * 64) return;
    int lane = u & 63, kc = (u >> 6) & 3, nt = (u >> 8) & 7, t = u >> 11;
    int quad = lane >> 4, lr = lane & 15;
    short8 s;
#pragma unroll
    for (int j = 0; j < 8; ++j)
        s[j] = (short)f2bfbits(w[(size_t)(t * 128 + kc * 32 + quad * 8 + j) * 128
                                 + nt * 16 + lr]);
    wp[u] = s;
}

// ---- x [N,128] f32 -> bf16 packed u32 pairs: xbu[n*64+l] = ch(2l, 2l+1) ----
__global__ __launch_bounds__(256) void pack_x(const float* __restrict__ x,
                                              unsigned int* __restrict__ xbu,
                                              long total4)
{
    for (size_t v = (size_t)blockIdx.x * 256 + threadIdx.x; v < (size_t)total4;
         v += (size_t)gridDim.x * 256) {
        f32x4 t = *(const f32x4*)(x + v * 4);
        xbu[v * 2]     = pk_bf16(t[0], t[1]);
        xbu[v * 2 + 1] = pk_bf16(t[2], t[3]);
    }
}

// ---- index width autodetect ----
__global__ void flag_k(const int* __restrict__ row, int* __restrict__ flag)
{
    if (threadIdx.x == 0 && blockIdx.x == 0) {
        int s = 0;
#pragma unroll
        for (int i = 1; i < 64; i += 2) s |= row[i];
        flag[0] = (s == 0) ? 1 : 0;
    }
}
__device__ inline int idx_at(const int* __restrict__ p, int e, int mode) {
    return p[mode ? (e << 1) : e];
}

// ---- bucket into meta rows; 1 atomic/edge; t=6 dead (self slot overwritten) ----
__global__ void edge_k(const int* __restrict__ row, const int* __restrict__ col,
                       const int* __restrict__ et, const int* __restrict__ flag,
                       unsigned int* __restrict__ meta, int* __restrict__ ovf,
                       int* __restrict__ novf, int E, int N)
{
    int e = blockIdx.x * blockDim.x + threadIdx.x;
    if (e >= E) return;
    const int mode = flag[0];
    int r = idx_at(row, e, mode);
    int c = idx_at(col, e, mode);
    int t = idx_at(et,  e, mode);
    if ((unsigned)r >= (unsigned)N || (unsigned)c >= (unsigned)N || (unsigned)t >= 6u)
        return;
    unsigned pos = atomicAdd(&meta[(size_t)r * ROWW + 7], 1u);
    if (pos < BUCKET_CAP) {
        meta[(size_t)r * ROWW + 8 + pos] = (unsigned)((c << 3) | t);
    } else {
        atomicAdd(&meta[(size_t)r * ROWW + t], 1u);   // overflow-only type count
        ovf[atomicAdd(novf, 1)] = e;
    }
}

// ---- fused gather(xb)->means->LDS->GEMM(wp)->out + BN stats. ----
// 16 nodes/block, 8 waves (512 thr): 2 nodes/wave phase-1, 1 ntile/wave phase-2.
__global__ __launch_bounds__(512, 8) void fused_k(
    const unsigned int* __restrict__ meta, const unsigned int* __restrict__ xbu,
    const uint4* __restrict__ wpq, float* __restrict__ out,
    float* __restrict__ statsR, int N)
{
    __shared__ unsigned int cold[TNODES * LROW];   // 28928 B; 4 blocks/CU (wave cap)
    const int tid  = threadIdx.x;
    const int l    = tid & 63;
    const int wv   = tid >> 6;                     // 0..7
    const int quad = l >> 4, lr = l & 15;
    const int tile = blockIdx.x * TNODES;
    const int base = tile + wv * 2;

    // ================= phase 1: per-node type-means (2 nodes/wave) =========
    unsigned mv = 0, self = 0;
    if (base < N) {
        mv   = (l < 40) ? meta[(size_t)base * ROWW + l] : 0u;
        self = xbu[(size_t)base * 64 + l];
    }
#pragma unroll
    for (int i = 0; i < 2; ++i) {
        const int r = base + i;
        if (r < N) {
            const unsigned fl = __shfl(mv, 7);
            const int nE = __builtin_amdgcn_readfirstlane(
                               (int)min(fl, (unsigned)BUCKET_CAP));
            const unsigned sv   = self;
            const unsigned mcur = mv;

            float acc[6][2];
#pragma unroll
            for (int t = 0; t < 6; ++t) { acc[t][0] = 0.f; acc[t][1] = 0.f; }

            // batch 0: up to 8 edge loads in flight before any consume
            unsigned q[8]; int pj[8];
#pragma unroll
            for (int j = 0; j < 8; ++j)
                if (j < nE) {                       // wave-uniform branch
                    pj[j] = (int)__shfl(mcur, 8 + j);
                    q[j]  = xbu[(size_t)(pj[j] >> 3) * 64 + l];
                }
            // prefetch next node metadata under the edge-load latency
            if (i == 0 && r + 1 < N) {
                mv   = (l < 40) ? meta[(size_t)(r + 1) * ROWW + l] : 0u;
                self = xbu[(size_t)(r + 1) * 64 + l];
            }
#pragma unroll
            for (int j = 0; j < 8; ++j)
                if (j < nE) {
                    float lo = bflo(q[j]), hi = bfhi(q[j]);
                    switch (__builtin_amdgcn_readfirstlane(pj[j] & 7)) {
                        case 0: acc[0][0] += lo; acc[0][1] += hi; break;
                        case 1: acc[1][0] += lo; acc[1][1] += hi; break;
                        case 2: acc[2][0] += lo; acc[2][1] += hi; break;
                        case 3: acc[3][0] += lo; acc[3][1] += hi; break;
                        case 4: acc[4][0] += lo; acc[4][1] += hi; break;
                        default: acc[5][0] += lo; acc[5][1] += hi; break;
                    }
                }
            // rare tail: degree > 8
            for (int k = 8; k < nE; k += 8) {
                const int rem = nE - k;
#pragma unroll
                for (int j = 0; j < 8; ++j)
                    if (j < rem) {
                        pj[j] = (int)__shfl(mcur, 8 + k + j);
                        q[j]  = xbu[(size_t)(pj[j] >> 3) * 64 + l];
                    }
#pragma unroll
                for (int j = 0; j < 8; ++j)
                    if (j < rem) {
                        float lo = bflo(q[j]), hi = bfhi(q[j]);
                        switch (__builtin_amdgcn_readfirstlane(pj[j] & 7)) {
                            case 0: acc[0][0] += lo; acc[0][1] += hi; break;
                            case 1: acc[1][0] += lo; acc[1][1] += hi; break;
                            case 2: acc[2][0] += lo; acc[2][1] += hi; break;
                            case 3: acc[3][0] += lo; acc[3][1] += hi; break;
                            case 4: acc[4][0] += lo; acc[4][1] += hi; break;
                            default: acc[5][0] += lo; acc[5][1] += hi; break;
                        }
                    }
            }

            // per-type counts: ballot over in-bucket payloads (+ rare ovf words)
            const bool inb = (l >= 8) && (l < 8 + nE);
            int c0 = (int)__popcll(__ballot(inb && ((mcur & 7u) == 0u)));
            int c1 = (int)__popcll(__ballot(inb && ((mcur & 7u) == 1u)));
            int c2 = (int)__popcll(__ballot(inb && ((mcur & 7u) == 2u)));
            int c3 = (int)__popcll(__ballot(inb && ((mcur & 7u) == 3u)));
            int c4 = (int)__popcll(__ballot(inb && ((mcur & 7u) == 4u)));
            int c5 = (int)__popcll(__ballot(inb && ((mcur & 7u) == 5u)));
            if (fl > (unsigned)BUCKET_CAP) {        // essentially never
                c0 += (int)__shfl(mcur, 0); c1 += (int)__shfl(mcur, 1);
                c2 += (int)__shfl(mcur, 2); c3 += (int)__shfl(mcur, 3);
                c4 += (int)__shfl(mcur, 4); c5 += (int)__shfl(mcur, 5);
            }
            const float iv0 = 1.0f / (float)max(c0, 1);
            const float iv1 = 1.0f / (float)max(c1, 1);
            const float iv2 = 1.0f / (float)max(c2, 1);
            const float iv3 = 1.0f / (float)max(c3, 1);
            const float iv4 = 1.0f / (float)max(c4, 1);
            const float iv5 = 1.0f / (float)max(c5, 1);

            // means -> LDS (bf16 pairs); self slot (t=6) = xb row verbatim
            const int mrow = (wv * 2 + i) * LROW;
            cold[mrow + 0 * 64 + l] = pk_bf16(acc[0][0] * iv0, acc[0][1] * iv0);
            cold[mrow + 1 * 64 + l] = pk_bf16(acc[1][0] * iv1, acc[1][1] * iv1);
            cold[mrow + 2 * 64 + l] = pk_bf16(acc[2][0] * iv2, acc[2][1] * iv2);
            cold[mrow + 3 * 64 + l] = pk_bf16(acc[3][0] * iv3, acc[3][1] * iv3);
            cold[mrow + 4 * 64 + l] = pk_bf16(acc[4][0] * iv4, acc[4][1] * iv4);
            cold[mrow + 5 * 64 + l] = pk_bf16(acc[5][0] * iv5, acc[5][1] * iv5);
            cold[mrow + 6 * 64 + l] = sv;
        }
    }
    __syncthreads();

    // ================= phase 2: [16,896] @ [896,16] per wave ===============
    f32x4 oa = (f32x4){0.f, 0.f, 0.f, 0.f};
    for (int t = 0; t < 7; ++t) {
#pragma unroll
        for (int kc = 0; kc < 4; ++kc) {
            BFrag a, b;
            const int ko = t * 64 + kc * 16 + quad * 4;
            a.q = *(const uint4*)&cold[lr * LROW + ko];
            b.q = wpq[(size_t)(((t * 8 + wv) * 4 + kc) * 64) + l];
            oa = __builtin_amdgcn_mfma_f32_16x16x32_bf16(a.b, b.b, oa, 0, 0, 0);
        }
    }
    // epilogue + fused BN stats. C/D: col=lr -> ch=wv*16+lr, row=quad*4+j -> node
    float s = 0.f, s2 = 0.f;
    const int ch = wv * 16 + lr;
#pragma unroll
    for (int j = 0; j < 4; ++j) {
        int m = tile + quad * 4 + j;
        if (m < N) {
            float v = oa[j];
            out[(size_t)m * 128 + ch] = v;
            s += v; s2 += v * v;
        }
    }
    s  += __shfl_xor(s, 16);  s  += __shfl_xor(s, 32);   // reduce across quads
    s2 += __shfl_xor(s2, 16); s2 += __shfl_xor(s2, 32);
    if (l < 16) {
        float* st = statsR + (size_t)(blockIdx.x & 7) * 256;   // 8 replicas
        atomicAdd(&st[ch],       s);
        atomicAdd(&st[128 + ch], s2);
    }
}

// ---- overflow repair: matvec xb[c]@W[t]/cnt -> out AND stats (replica 0) ----
__global__ void ovf_k(const int* __restrict__ ovf, const int* __restrict__ novf,
                      const int* __restrict__ row, const int* __restrict__ col,
                      const int* __restrict__ et, const int* __restrict__ flag,
                      const unsigned int* __restrict__ xbu,
                      const unsigned int* __restrict__ meta,
                      const float* __restrict__ w,
                      float* __restrict__ out, float* __restrict__ statsR,
                      int nwaves)
{
    const int n = novf[0];
    if (n == 0) return;
    const int mode = flag[0];
    const int l = threadIdx.x & 63;
    for (int i = (blockIdx.x * 256 + threadIdx.x) >> 6; i < n; i += nwaves) {
        int e = ovf[i];
        int r = idx_at(row, e, mode);
        int c = idx_at(col, e, mode);
        int t = idx_at(et,  e, mode);
        // exact count = in-bucket ballot + overflow word
        unsigned mv = (l < 40) ? meta[(size_t)r * ROWW + l] : 0u;
        unsigned fl = __shfl(mv, 7);
        int nE = (int)min(fl, (unsigned)BUCKET_CAP);
        bool inb = (l >= 8) && (l < 8 + nE);
        int ct = (int)__popcll(__ballot(inb && ((int)(mv & 7u) == t)))
               + (int)__shfl(mv, t);
        float inv = 1.0f / (float)max(ct, 1);
        float d0 = 0.f, d1 = 0.f;
        for (int k = 0; k < 64; ++k) {
            unsigned xv = xbu[(size_t)c * 64 + k];
            float xlo = bflo(xv), xhi = bfhi(xv);
            const float* wr = w + (size_t)(t * 128 + 2 * k) * 128;
            d0 += xlo * wr[2 * l]     + xhi * wr[128 + 2 * l];
            d1 += xlo * wr[2 * l + 1] + xhi * wr[128 + 2 * l + 1];
        }
        d0 *= inv; d1 *= inv;
        float olo = atomicAdd(&out[(size_t)r * 128 + 2 * l],     d0);
        float ohi = atomicAdd(&out[(size_t)r * 128 + 2 * l + 1], d1);
        atomicAdd(&statsR[2 * l],           d0);
        atomicAdd(&statsR[128 + 2 * l],     d0 * (2.f * olo + d0));
        atomicAdd(&statsR[2 * l + 1],       d1);
        atomicAdd(&statsR[128 + 2 * l + 1], d1 * (2.f * ohi + d1));
    }
}

// ---- BN finalize: sums 8 stat replicas; coalesced vec4; no LDS ----
__global__ __launch_bounds__(256) void norm_k(
    float* __restrict__ out, const float* __restrict__ statsR,
    const float* __restrict__ gamma, const float* __restrict__ beta, int N)
{
    const int c0 = (threadIdx.x * 4) & 127;     // grid stride is mult. of 128 elems
    const float invN = 1.0f / (float)N;
    f32x4 sc, bi;
#pragma unroll
    for (int j = 0; j < 4; ++j) {
        int c = c0 + j;
        float sm = 0.f, sq = 0.f;
#pragma unroll
        for (int rep = 0; rep < 8; ++rep) {
            sm += statsR[rep * 256 + c];
            sq += statsR[rep * 256 + 128 + c];
        }
        float mean = sm * invN;
        float var  = sq * invN - mean * mean;
        float s = gamma[c] * rsqrtf(var + 1e-5f);
        sc[j] = s; bi[j] = beta[c] - mean * s;
    }
    const size_t nv = (size_t)N * 32;           // vec4 count
    for (size_t v = (size_t)blockIdx.x * 256 + threadIdx.x; v < nv;
         v += (size_t)gridDim.x * 256) {
        f32x4 x = *(f32x4*)(out + v * 4);
#pragma unroll
        for (int j = 0; j < 4; ++j) x[j] = x[j] * sc[j] + bi[j];
        *(f32x4*)(out + v * 4) = x;
    }
}

extern "C" void kernel_launch(void* const* d_in, const int* in_sizes, int n_in,
                              void* d_out, int out_size, void* d_ws, size_t ws_size,
                              hipStream_t stream)
{
    const float* x     = (const float*)d_in[0];
    const int*   row   = (const int*)d_in[1];
    const int*   col   = (const int*)d_in[2];
    const int*   etype = (const int*)d_in[3];
    const float* w     = (const float*)d_in[4];
    const float* gamma = (const float*)d_in[5];
    const float* beta  = (const float*)d_in[6];
    float* out = (float*)d_out;

    const int N = in_sizes[0] / 128;   // 100000
    const int E = in_sizes[1];         // 700000

    char* ws = (char*)d_ws;
    unsigned int* xbu   = (unsigned int*)ws;                             // N*64 u32
    short8*       wp    = (short8*)(ws + (size_t)N * 256);               // 229376 B
    unsigned int* meta  = (unsigned int*)((char*)wp + 7 * 8 * 4 * 64 * 16); // N*48 u32
    int*          ovf   = (int*)((char*)meta + (size_t)N * ROWW * 4 + 256); // E int
    float*        stats = (float*)((char*)ovf + (size_t)E * 4);          // 8*256 f32
    int*          flag  = (int*)((char*)stats + 8 * 256 * 4);            // 1 int
    int*          novf  = flag + 1;                                      // 1 int

    hipMemsetAsync(meta,  0, (size_t)N * ROWW * 4, stream);
    hipMemsetAsync(stats, 0, 8 * 256 * 4 + 8,      stream);

    flag_k<<<1, 64, 0, stream>>>(row, flag);
    pack_w<<<(7 * 8 * 4 * 64 + 255) / 256, 256, 0, stream>>>(w, wp);
    pack_x<<<2048, 256, 0, stream>>>(x, xbu, (long)N * 32);
    edge_k<<<(E + 255) / 256, 256, 0, stream>>>(row, col, etype, flag,
                                                meta, ovf, novf, E, N);
    fused_k<<<(N + TNODES - 1) / TNODES, 512, 0, stream>>>(meta, xbu,
                                                           (const uint4*)wp, out,
                                                           stats, N);
    ovf_k<<<64, 256, 0, stream>>>(ovf, novf, row, col, etype, flag,
                                  xbu, meta, w, out, stats, 256);
    norm_k<<<2048, 256, 0, stream>>>(out, stats, gamma, beta, N);
}

// Round 6
// 264.483 us; speedup vs baseline: 1.5768x; 1.0012x over previous
//
#include <hip/hip_runtime.h>
#include <hip/hip_bf16.h>

// GraphConvNorm: scatter-mean by (row*7+edge_type) -> [N,896]@[896,128] -> BatchNorm.
// N=100000, C=128, E=700000. x/w/gamma/beta f32, indices auto int32/int64, out f32.
// r12: 512-thr/8-wave blocks, merged meta row (1 req/node), ballot type-counts,
// fused BN stats. Occ 48->74% BUT fused_k 101->113us: VGPR 44->32 (launch_bounds
// 512,8) made the allocator serialize the batch-8 edge loads (per-wave req rate
// halved 2.8->1.3 M/s). r13: restore MLP under the 64-VGPR budget:
// (a) branch-free clamped batch-8 issue (shfl lane min(j,nE-1), single clause,
//     8 loads always in flight), consume zeroed for j>=nE (branchless, exact);
// (b) phase-2 split into two independent MFMA accumulator chains (t0-3 / t4-6).
// ws: xb 25.6MB + wp 0.23 + meta 19.2MB + ovf 2.8 + stats 8KB.

typedef float  f32x4  __attribute__((ext_vector_type(4)));
typedef short  short8 __attribute__((ext_vector_type(8)));
typedef __bf16 bf16x8 __attribute__((ext_vector_type(8)));

union BFrag { uint4 q; short8 s; bf16x8 b; unsigned int u[4]; };

__device__ inline unsigned short f2bfbits(float f) {
    union { float f; unsigned int u; } v; v.f = f;
    unsigned int u = v.u;
    u += 0x7fffu + ((u >> 16) & 1u);   // RNE
    return (unsigned short)(u >> 16);
}
__device__ inline unsigned int pk_bf16(float lo, float hi) {
    float2 f; f.x = lo; f.y = hi;
    union { __hip_bfloat162 h; unsigned int u; } v;
    v.h = __float22bfloat162_rn(f);
    return v.u;
}
__device__ inline float bflo(unsigned int p) {
    union { unsigned int u; float f; } v; v.u = p << 16; return v.f;
}
__device__ inline float bfhi(unsigned int p) {
    union { unsigned int u; float f; } v; v.u = p & 0xffff0000u; return v.f;
}

#define BUCKET_CAP 32
#define ROWW 48          // meta row: 0-6 ovf-cnt, 7 fill, 8-39 payload, 40-47 pad
#define LROW 452         // LDS row u32 (448 data + 4 pad)
#define TNODES 16

// ---- W [7*128,128] f32 -> bf16 in MFMA B-frag order: [t][nt][kc][lane][j] ----
__global__ void pack_w(const float* __restrict__ w, short8* __restrict__ wp)
{
    int u = blockIdx.x * 256 + threadIdx.x;
    if (u >= 7 * 8 * 4 * 64) return;
    int lane = u & 63, kc = (u >> 6) & 3, nt = (u >> 8) & 7, t = u >> 11;
    int quad = lane >> 4, lr = lane & 15;
    short8 s;
#pragma unroll
    for (int j = 0; j < 8; ++j)
        s[j] = (short)f2bfbits(w[(size_t)(t * 128 + kc * 32 + quad * 8 + j) * 128
                                 + nt * 16 + lr]);
    wp[u] = s;
}

// ---- x [N,128] f32 -> bf16 packed u32 pairs: xbu[n*64+l] = ch(2l, 2l+1) ----
__global__ __launch_bounds__(256) void pack_x(const float* __restrict__ x,
                                              unsigned int* __restrict__ xbu,
                                              long total4)
{
    for (size_t v = (size_t)blockIdx.x * 256 + threadIdx.x; v < (size_t)total4;
         v += (size_t)gridDim.x * 256) {
        f32x4 t = *(const f32x4*)(x + v * 4);
        xbu[v * 2]     = pk_bf16(t[0], t[1]);
        xbu[v * 2 + 1] = pk_bf16(t[2], t[3]);
    }
}

// ---- index width autodetect ----
__global__ void flag_k(const int* __restrict__ row, int* __restrict__ flag)
{
    if (threadIdx.x == 0 && blockIdx.x == 0) {
        int s = 0;
#pragma unroll
        for (int i = 1; i < 64; i += 2) s |= row[i];
        flag[0] = (s == 0) ? 1 : 0;
    }
}
__device__ inline int idx_at(const int* __restrict__ p, int e, int mode) {
    return p[mode ? (e << 1) : e];
}

// ---- bucket into meta rows; 1 atomic/edge; t=6 dead (self slot overwritten) ----
__global__ void edge_k(const int* __restrict__ row, const int* __restrict__ col,
                       const int* __restrict__ et, const int* __restrict__ flag,
                       unsigned int* __restrict__ meta, int* __restrict__ ovf,
                       int* __restrict__ novf, int E, int N)
{
    int e = blockIdx.x * blockDim.x + threadIdx.x;
    if (e >= E) return;
    const int mode = flag[0];
    int r = idx_at(row, e, mode);
    int c = idx_at(col, e, mode);
    int t = idx_at(et,  e, mode);
    if ((unsigned)r >= (unsigned)N || (unsigned)c >= (unsigned)N || (unsigned)t >= 6u)
        return;
    unsigned pos = atomicAdd(&meta[(size_t)r * ROWW + 7], 1u);
    if (pos < BUCKET_CAP) {
        meta[(size_t)r * ROWW + 8 + pos] = (unsigned)((c << 3) | t);
    } else {
        atomicAdd(&meta[(size_t)r * ROWW + t], 1u);   // overflow-only type count
        ovf[atomicAdd(novf, 1)] = e;
    }
}

// ---- fused gather(xb)->means->LDS->GEMM(wp)->out + BN stats. ----
// 16 nodes/block, 8 waves (512 thr): 2 nodes/wave phase-1, 1 ntile/wave phase-2.
__global__ __launch_bounds__(512, 8) void fused_k(
    const unsigned int* __restrict__ meta, const unsigned int* __restrict__ xbu,
    const uint4* __restrict__ wpq, float* __restrict__ out,
    float* __restrict__ statsR, int N)
{
    __shared__ unsigned int cold[TNODES * LROW];   // 28928 B; 4 blocks/CU (wave cap)
    const int tid  = threadIdx.x;
    const int l    = tid & 63;
    const int wv   = tid >> 6;                     // 0..7
    const int quad = l >> 4, lr = l & 15;
    const int tile = blockIdx.x * TNODES;
    const int base = tile + wv * 2;

    // ================= phase 1: per-node type-means (2 nodes/wave) =========
    unsigned mv = 0, self = 0;
    if (base < N) {
        mv   = (l < 40) ? meta[(size_t)base * ROWW + l] : 0u;
        self = xbu[(size_t)base * 64 + l];
    }
#pragma unroll
    for (int i = 0; i < 2; ++i) {
        const int r = base + i;
        if (r < N) {
            const unsigned fl = __shfl(mv, 7);
            const int nE = __builtin_amdgcn_readfirstlane(
                               (int)min(fl, (unsigned)BUCKET_CAP));
            const unsigned sv   = self;
            const unsigned mcur = mv;

            float acc[6][2];
#pragma unroll
            for (int t = 0; t < 6; ++t) { acc[t][0] = 0.f; acc[t][1] = 0.f; }

            // batch 0: 8 clamped loads, branch-free single clause -> all in flight
            unsigned q[8]; int pj[8];
            if (nE > 0) {
#pragma unroll
                for (int j = 0; j < 8; ++j) {
                    pj[j] = (int)__shfl(mcur, 8 + min(j, nE - 1));
                    q[j]  = xbu[(size_t)(pj[j] >> 3) * 64 + l];
                }
            }
            // prefetch next node metadata under the edge-load latency
            if (i == 0 && r + 1 < N) {
                mv   = (l < 40) ? meta[(size_t)(r + 1) * ROWW + l] : 0u;
                self = xbu[(size_t)(r + 1) * 64 + l];
            }
            if (nE > 0) {
#pragma unroll
                for (int j = 0; j < 8; ++j) {
                    unsigned qq = (j < nE) ? q[j] : 0u;   // zeroed dup: adds 0
                    float lo = bflo(qq), hi = bfhi(qq);
                    switch (__builtin_amdgcn_readfirstlane(pj[j] & 7)) {
                        case 0: acc[0][0] += lo; acc[0][1] += hi; break;
                        case 1: acc[1][0] += lo; acc[1][1] += hi; break;
                        case 2: acc[2][0] += lo; acc[2][1] += hi; break;
                        case 3: acc[3][0] += lo; acc[3][1] += hi; break;
                        case 4: acc[4][0] += lo; acc[4][1] += hi; break;
                        default: acc[5][0] += lo; acc[5][1] += hi; break;
                    }
                }
                // rare tail: degree > 8
                for (int k = 8; k < nE; k += 8) {
                    const int rem = nE - k;
#pragma unroll
                    for (int j = 0; j < 8; ++j) {
                        pj[j] = (int)__shfl(mcur, 8 + k + min(j, rem - 1));
                        q[j]  = xbu[(size_t)(pj[j] >> 3) * 64 + l];
                    }
#pragma unroll
                    for (int j = 0; j < 8; ++j) {
                        unsigned qq = (j < rem) ? q[j] : 0u;
                        float lo = bflo(qq), hi = bfhi(qq);
                        switch (__builtin_amdgcn_readfirstlane(pj[j] & 7)) {
                            case 0: acc[0][0] += lo; acc[0][1] += hi; break;
                            case 1: acc[1][0] += lo; acc[1][1] += hi; break;
                            case 2: acc[2][0] += lo; acc[2][1] += hi; break;
                            case 3: acc[3][0] += lo; acc[3][1] += hi; break;
                            case 4: acc[4][0] += lo; acc[4][1] += hi; break;
                            default: acc[5][0] += lo; acc[5][1] += hi; break;
                        }
                    }
                }
            }

            // per-type counts: ballot over in-bucket payloads (+ rare ovf words)
            const bool inb = (l >= 8) && (l < 8 + nE);
            int c0 = (int)__popcll(__ballot(inb && ((mcur & 7u) == 0u)));
            int c1 = (int)__popcll(__ballot(inb && ((mcur & 7u) == 1u)));
            int c2 = (int)__popcll(__ballot(inb && ((mcur & 7u) == 2u)));
            int c3 = (int)__popcll(__ballot(inb && ((mcur & 7u) == 3u)));
            int c4 = (int)__popcll(__ballot(inb && ((mcur & 7u) == 4u)));
            int c5 = (int)__popcll(__ballot(inb && ((mcur & 7u) == 5u)));
            if (fl > (unsigned)BUCKET_CAP) {        // essentially never
                c0 += (int)__shfl(mcur, 0); c1 += (int)__shfl(mcur, 1);
                c2 += (int)__shfl(mcur, 2); c3 += (int)__shfl(mcur, 3);
                c4 += (int)__shfl(mcur, 4); c5 += (int)__shfl(mcur, 5);
            }
            const float iv0 = 1.0f / (float)max(c0, 1);
            const float iv1 = 1.0f / (float)max(c1, 1);
            const float iv2 = 1.0f / (float)max(c2, 1);
            const float iv3 = 1.0f / (float)max(c3, 1);
            const float iv4 = 1.0f / (float)max(c4, 1);
            const float iv5 = 1.0f / (float)max(c5, 1);

            // means -> LDS (bf16 pairs); self slot (t=6) = xb row verbatim
            const int mrow = (wv * 2 + i) * LROW;
            cold[mrow + 0 * 64 + l] = pk_bf16(acc[0][0] * iv0, acc[0][1] * iv0);
            cold[mrow + 1 * 64 + l] = pk_bf16(acc[1][0] * iv1, acc[1][1] * iv1);
            cold[mrow + 2 * 64 + l] = pk_bf16(acc[2][0] * iv2, acc[2][1] * iv2);
            cold[mrow + 3 * 64 + l] = pk_bf16(acc[3][0] * iv3, acc[3][1] * iv3);
            cold[mrow + 4 * 64 + l] = pk_bf16(acc[4][0] * iv4, acc[4][1] * iv4);
            cold[mrow + 5 * 64 + l] = pk_bf16(acc[5][0] * iv5, acc[5][1] * iv5);
            cold[mrow + 6 * 64 + l] = sv;
        }
    }
    __syncthreads();

    // ======== phase 2: [16,896] @ [896,16] per wave, 2 indep MFMA chains ====
    f32x4 oa0 = (f32x4){0.f, 0.f, 0.f, 0.f};
    f32x4 oa1 = (f32x4){0.f, 0.f, 0.f, 0.f};
#pragma unroll
    for (int t = 0; t < 4; ++t)
#pragma unroll
        for (int kc = 0; kc < 4; ++kc) {
            BFrag a, b;
            const int ko = t * 64 + kc * 16 + quad * 4;
            a.q = *(const uint4*)&cold[lr * LROW + ko];
            b.q = wpq[(size_t)(((t * 8 + wv) * 4 + kc) * 64) + l];
            oa0 = __builtin_amdgcn_mfma_f32_16x16x32_bf16(a.b, b.b, oa0, 0, 0, 0);
        }
#pragma unroll
    for (int t = 4; t < 7; ++t)
#pragma unroll
        for (int kc = 0; kc < 4; ++kc) {
            BFrag a, b;
            const int ko = t * 64 + kc * 16 + quad * 4;
            a.q = *(const uint4*)&cold[lr * LROW + ko];
            b.q = wpq[(size_t)(((t * 8 + wv) * 4 + kc) * 64) + l];
            oa1 = __builtin_amdgcn_mfma_f32_16x16x32_bf16(a.b, b.b, oa1, 0, 0, 0);
        }
    // epilogue + fused BN stats. C/D: col=lr -> ch=wv*16+lr, row=quad*4+j -> node
    float s = 0.f, s2 = 0.f;
    const int ch = wv * 16 + lr;
#pragma unroll
    for (int j = 0; j < 4; ++j) {
        int m = tile + quad * 4 + j;
        if (m < N) {
            float v = oa0[j] + oa1[j];
            out[(size_t)m * 128 + ch] = v;
            s += v; s2 += v * v;
        }
    }
    s  += __shfl_xor(s, 16);  s  += __shfl_xor(s, 32);   // reduce across quads
    s2 += __shfl_xor(s2, 16); s2 += __shfl_xor(s2, 32);
    if (l < 16) {
        float* st = statsR + (size_t)(blockIdx.x & 7) * 256;   // 8 replicas
        atomicAdd(&st[ch],       s);
        atomicAdd(&st[128 + ch], s2);
    }
}

// ---- overflow repair: matvec xb[c]@W[t]/cnt -> out AND stats (replica 0) ----
__global__ void ovf_k(const int* __restrict__ ovf, const int* __restrict__ novf,
                      const int* __restrict__ row, const int* __restrict__ col,
                      const int* __restrict__ et, const int* __restrict__ flag,
                      const unsigned int* __restrict__ xbu,
                      const unsigned int* __restrict__ meta,
                      const float* __restrict__ w,
                      float* __restrict__ out, float* __restrict__ statsR,
                      int nwaves)
{
    const int n = novf[0];
    if (n == 0) return;
    const int mode = flag[0];
    const int l = threadIdx.x & 63;
    for (int i = (blockIdx.x * 256 + threadIdx.x) >> 6; i < n; i += nwaves) {
        int e = ovf[i];
        int r = idx_at(row, e, mode);
        int c = idx_at(col, e, mode);
        int t = idx_at(et,  e, mode);
        // exact count = in-bucket ballot + overflow word
        unsigned mv = (l < 40) ? meta[(size_t)r * ROWW + l] : 0u;
        unsigned fl = __shfl(mv, 7);
        int nE = (int)min(fl, (unsigned)BUCKET_CAP);
        bool inb = (l >= 8) && (l < 8 + nE);
        int ct = (int)__popcll(__ballot(inb && ((int)(mv & 7u) == t)))
               + (int)__shfl(mv, t);
        float inv = 1.0f / (float)max(ct, 1);
        float d0 = 0.f, d1 = 0.f;
        for (int k = 0; k < 64; ++k) {
            unsigned xv = xbu[(size_t)c * 64 + k];
            float xlo = bflo(xv), xhi = bfhi(xv);
            const float* wr = w + (size_t)(t * 128 + 2 * k) * 128;
            d0 += xlo * wr[2 * l]     + xhi * wr[128 + 2 * l];
            d1 += xlo * wr[2 * l + 1] + xhi * wr[128 + 2 * l + 1];
        }
        d0 *= inv; d1 *= inv;
        float olo = atomicAdd(&out[(size_t)r * 128 + 2 * l],     d0);
        float ohi = atomicAdd(&out[(size_t)r * 128 + 2 * l + 1], d1);
        atomicAdd(&statsR[2 * l],           d0);
        atomicAdd(&statsR[128 + 2 * l],     d0 * (2.f * olo + d0));
        atomicAdd(&statsR[2 * l + 1],       d1);
        atomicAdd(&statsR[128 + 2 * l + 1], d1 * (2.f * ohi + d1));
    }
}

// ---- BN finalize: sums 8 stat replicas; coalesced vec4; no LDS ----
__global__ __launch_bounds__(256) void norm_k(
    float* __restrict__ out, const float* __restrict__ statsR,
    const float* __restrict__ gamma, const float* __restrict__ beta, int N)
{
    const int c0 = (threadIdx.x * 4) & 127;     // grid stride is mult. of 128 elems
    const float invN = 1.0f / (float)N;
    f32x4 sc, bi;
#pragma unroll
    for (int j = 0; j < 4; ++j) {
        int c = c0 + j;
        float sm = 0.f, sq = 0.f;
#pragma unroll
        for (int rep = 0; rep < 8; ++rep) {
            sm += statsR[rep * 256 + c];
            sq += statsR[rep * 256 + 128 + c];
        }
        float mean = sm * invN;
        float var  = sq * invN - mean * mean;
        float s = gamma[c] * rsqrtf(var + 1e-5f);
        sc[j] = s; bi[j] = beta[c] - mean * s;
    }
    const size_t nv = (size_t)N * 32;           // vec4 count
    for (size_t v = (size_t)blockIdx.x * 256 + threadIdx.x; v < nv;
         v += (size_t)gridDim.x * 256) {
        f32x4 x = *(f32x4*)(out + v * 4);
#pragma unroll
        for (int j = 0; j < 4; ++j) x[j] = x[j] * sc[j] + bi[j];
        *(f32x4*)(out + v * 4) = x;
    }
}

extern "C" void kernel_launch(void* const* d_in, const int* in_sizes, int n_in,
                              void* d_out, int out_size, void* d_ws, size_t ws_size,
                              hipStream_t stream)
{
    const float* x     = (const float*)d_in[0];
    const int*   row   = (const int*)d_in[1];
    const int*   col   = (const int*)d_in[2];
    const int*   etype = (const int*)d_in[3];
    const float* w     = (const float*)d_in[4];
    const float* gamma = (const float*)d_in[5];
    const float* beta  = (const float*)d_in[6];
    float* out = (float*)d_out;

    const int N = in_sizes[0] / 128;   // 100000
    const int E = in_sizes[1];         // 700000

    char* ws = (char*)d_ws;
    unsigned int* xbu   = (unsigned int*)ws;                             // N*64 u32
    short8*       wp    = (short8*)(ws + (size_t)N * 256);               // 229376 B
    unsigned int* meta  = (unsigned int*)((char*)wp + 7 * 8 * 4 * 64 * 16); // N*48 u32
    int*          ovf   = (int*)((char*)meta + (size_t)N * ROWW * 4 + 256); // E int
    float*        stats = (float*)((char*)ovf + (size_t)E * 4);          // 8*256 f32
    int*          flag  = (int*)((char*)stats + 8 * 256 * 4);            // 1 int
    int*          novf  = flag + 1;                                      // 1 int

    hipMemsetAsync(meta,  0, (size_t)N * ROWW * 4, stream);
    hipMemsetAsync(stats, 0, 8 * 256 * 4 + 8,      stream);

    flag_k<<<1, 64, 0, stream>>>(row, flag);
    pack_w<<<(7 * 8 * 4 * 64 + 255) / 256, 256, 0, stream>>>(w, wp);
    pack_x<<<2048, 256, 0, stream>>>(x, xbu, (long)N * 32);
    edge_k<<<(E + 255) / 256, 256, 0, stream>>>(row, col, etype, flag,
                                                meta, ovf, novf, E, N);
    fused_k<<<(N + TNODES - 1) / TNODES, 512, 0, stream>>>(meta, xbu,
                                                           (const uint4*)wp, out,
                                                           stats, N);
    ovf_k<<<64, 256, 0, stream>>>(ovf, novf, row, col, etype, flag,
                                  xbu, meta, w, out, stats, 256);
    norm_k<<<2048, 256, 0, stream>>>(out, stats, gamma, beta, N);
}